// Round 8
// baseline (523.896 us; speedup 1.0000x reference)
//
#include <hip/hip_runtime.h>
#include <math.h>

#define N_NODES 100000
#define N_EDGES 1600000
#define N_GRAPHS 512
#define HID 64
#define NC 3

#define NBUCK 782        // ceil(100000/128) buckets of 128 nodes
#define EPB 8192         // edges per block in chist/partition
#define NPBLK 196        // ceil(1600000/8192)
#define BSTRIDE 4096     // col entries reserved per bucket (max padded bucket ~2600)
#define DUMMY N_NODES    // padded col entries point at a zeroed row

// ---------------- CSR build, atomic-light 2-level counting sort ----------------

__global__ __launch_bounds__(256) void chist_kernel(const int* __restrict__ dst,
                                                    int* __restrict__ cbins) {
    __shared__ int bins[NBUCK];
    for (int i = threadIdx.x; i < NBUCK; i += 256) bins[i] = 0;
    __syncthreads();
    int start = blockIdx.x * EPB;
    int endd = min(start + EPB, N_EDGES);
    for (int e = start + threadIdx.x; e < endd; e += 256)
        atomicAdd(&bins[dst[e] >> 7], 1);
    __syncthreads();
    for (int i = threadIdx.x; i < NBUCK; i += 256)
        if (bins[i]) atomicAdd(&cbins[i], bins[i]);
}

__global__ __launch_bounds__(1024) void cscan_kernel(const int* __restrict__ cbins,
                                                     int* __restrict__ cstart,
                                                     int* __restrict__ ccursor) {
    __shared__ int s[1024];
    int t = threadIdx.x;
    int v = (t < NBUCK) ? cbins[t] : 0;
    int val = v;
    s[t] = val;
    __syncthreads();
    for (int off = 1; off < 1024; off <<= 1) {
        int o = (t >= off) ? s[t - off] : 0;
        __syncthreads();
        val += o;
        s[t] = val;
        __syncthreads();
    }
    if (t < NBUCK) {
        int ex = val - v;
        cstart[t] = ex;
        ccursor[t] = ex;
    }
    if (t == 0) cstart[NBUCK] = N_EDGES;
}

__global__ __launch_bounds__(256) void partition_kernel(const int* __restrict__ src,
                                                        const int* __restrict__ dst,
                                                        int* __restrict__ ccursor,
                                                        int2* __restrict__ part) {
    __shared__ int cnt[NBUCK];
    __shared__ int base[NBUCK];
    __shared__ int cur[NBUCK];
    for (int i = threadIdx.x; i < NBUCK; i += 256) { cnt[i] = 0; cur[i] = 0; }
    __syncthreads();
    int start = blockIdx.x * EPB;
    int endd = min(start + EPB, N_EDGES);
    for (int e = start + threadIdx.x; e < endd; e += 256)
        atomicAdd(&cnt[dst[e] >> 7], 1);
    __syncthreads();
    for (int i = threadIdx.x; i < NBUCK; i += 256)
        base[i] = cnt[i] ? atomicAdd(&ccursor[i], cnt[i]) : 0;
    __syncthreads();
    for (int e = start + threadIdx.x; e < endd; e += 256) {
        int d = dst[e];
        int b = d >> 7;
        int r = atomicAdd(&cur[b], 1);
        part[base[b] + r] = make_int2(src[e], d);
    }
}

// Per bucket: LDS histogram of its 128 nodes, padded-to-8 prefix scan, ranked
// placement into col[bucket*BSTRIDE ...], pad slots filled with DUMMY.

__global__ __launch_bounds__(256) void bcsr_kernel(const int2* __restrict__ part,
                                                   const int* __restrict__ cstart,
                                                   int* __restrict__ row_ptr,
                                                   int* __restrict__ pdeg,
                                                   int* __restrict__ col) {
    __shared__ int deg[128];
    __shared__ int cur[128];
    __shared__ int pre[128];
    __shared__ int ss[256];
    int b = blockIdx.x;
    int t = threadIdx.x;
    int s0 = cstart[b], s1 = cstart[b + 1];
    if (t < 128) { deg[t] = 0; cur[t] = 0; }
    __syncthreads();
    for (int e = s0 + t; e < s1; e += 256)
        atomicAdd(&deg[part[e].y & 127], 1);
    __syncthreads();
    // padded degree, exclusive scan over 128 (Hillis-Steele over 256 slots)
    int v = (t < 128) ? ((deg[t] + 7) & ~7) : 0;
    int val = v;
    ss[t] = val;
    __syncthreads();
    for (int off = 1; off < 256; off <<= 1) {
        int o = (t >= off) ? ss[t - off] : 0;
        __syncthreads();
        val += o;
        ss[t] = val;
        __syncthreads();
    }
    if (t < 128) pre[t] = val - v;
    __syncthreads();
    int base = b * BSTRIDE;
    int node = b * 128 + t;
    if (t < 128 && node < N_NODES) {
        row_ptr[node] = base + pre[t];
        pdeg[node] = v;
    }
    for (int e = s0 + t; e < s1; e += 256) {
        int2 p = part[e];
        int nl = p.y & 127;
        int r = atomicAdd(&cur[nl], 1);
        col[base + pre[nl] + r] = p.x;
    }
    __syncthreads();
    if (t < 128) {
        for (int i = deg[t]; i < v; i++)
            col[base + pre[t] + i] = DUMMY;
    }
}

// ---------------- gather: agg[n] = sum_{e in row n} hin[col[e]] ----------------
// Wave = 4 nodes (16 lanes each, lane holds float4 of channels). Rows padded to
// multiple of 8 -> unconditional 8-deep pipeline, no tail. Dummy rows are zero.

__global__ __launch_bounds__(256) void gather_kernel(
    const float* __restrict__ hin, float* __restrict__ agg,
    const int* __restrict__ row_ptr, const int* __restrict__ pdeg,
    const int* __restrict__ col)
{
    int lane = threadIdx.x & 63;
    int slot = lane >> 4;          // 0..3 -> node within group
    int ch4  = (lane & 15) * 4;    // float4 channel base
    int gwid = (blockIdx.x * blockDim.x + threadIdx.x) >> 6;
    int nwaves = (gridDim.x * blockDim.x) >> 6;

    for (int n0 = gwid * 4; n0 < N_NODES; n0 += nwaves * 4) {
        int n = n0 + slot;
        int start = row_ptr[n];
        int pd = pdeg[n];
        const int* row = col + start;
        float4 a0 = {0.f,0.f,0.f,0.f}, a1 = {0.f,0.f,0.f,0.f};
        float4 a2 = {0.f,0.f,0.f,0.f}, a3 = {0.f,0.f,0.f,0.f};
        for (int e = 0; e < pd; e += 8) {
            int4 ca = *(const int4*)(row + e);
            int4 cb = *(const int4*)(row + e + 4);
            float4 v0 = *(const float4*)(hin + (size_t)ca.x * HID + ch4);
            float4 v1 = *(const float4*)(hin + (size_t)ca.y * HID + ch4);
            float4 v2 = *(const float4*)(hin + (size_t)ca.z * HID + ch4);
            float4 v3 = *(const float4*)(hin + (size_t)ca.w * HID + ch4);
            float4 v4 = *(const float4*)(hin + (size_t)cb.x * HID + ch4);
            float4 v5 = *(const float4*)(hin + (size_t)cb.y * HID + ch4);
            float4 v6 = *(const float4*)(hin + (size_t)cb.z * HID + ch4);
            float4 v7 = *(const float4*)(hin + (size_t)cb.w * HID + ch4);
            a0.x += v0.x + v4.x; a0.y += v0.y + v4.y; a0.z += v0.z + v4.z; a0.w += v0.w + v4.w;
            a1.x += v1.x + v5.x; a1.y += v1.y + v5.y; a1.z += v1.z + v5.z; a1.w += v1.w + v5.w;
            a2.x += v2.x + v6.x; a2.y += v2.y + v6.y; a2.z += v2.z + v6.z; a2.w += v2.w + v6.w;
            a3.x += v3.x + v7.x; a3.y += v3.y + v7.y; a3.z += v3.z + v7.z; a3.w += v3.w + v7.w;
        }
        a0.x += a1.x + a2.x + a3.x;
        a0.y += a1.y + a2.y + a3.y;
        a0.z += a1.z + a2.z + a3.z;
        a0.w += a1.w + a2.w + a3.w;
        *(float4*)(agg + (size_t)n * HID + ch4) = a0;
    }
}

// ---------------- transform: hout = relu(agg@Wrel + hin@Wroot + b) ----------------

#define TNODES 8

__global__ __launch_bounds__(256) void transform_kernel(
    const float* __restrict__ hin, const float* __restrict__ agg,
    float* __restrict__ hout,
    const float* __restrict__ Wrel, const float* __restrict__ Wroot,
    const float* __restrict__ bias)
{
    __shared__ float sW0[HID * HID];
    __shared__ float sW1[HID * HID];
    {
        const float4* wr4 = (const float4*)Wrel;
        const float4* wo4 = (const float4*)Wroot;
        float4* s0 = (float4*)sW0;
        float4* s1 = (float4*)sW1;
        for (int i = threadIdx.x; i < HID * HID / 4; i += blockDim.x) {
            s0[i] = wr4[i];
            s1[i] = wo4[i];
        }
    }
    __syncthreads();

    int lane = threadIdx.x & 63;
    int gwid = (blockIdx.x * blockDim.x + threadIdx.x) >> 6;
    int nwaves = (gridDim.x * blockDim.x) >> 6;
    float b = bias[lane];

    for (int n0 = gwid * TNODES; n0 < N_NODES; n0 += nwaves * TNODES) {
        float hv[TNODES], av[TNODES];
#pragma unroll
        for (int t = 0; t < TNODES; t++) {
            hv[t] = hin[(size_t)(n0 + t) * HID + lane];
            av[t] = agg[(size_t)(n0 + t) * HID + lane];
        }
        float out[TNODES];
#pragma unroll
        for (int t = 0; t < TNODES; t++) out[t] = b;
#pragma unroll
        for (int k = 0; k < HID; k++) {
            float wr = sW0[k * HID + lane];
            float wo = sW1[k * HID + lane];
#pragma unroll
            for (int t = 0; t < TNODES; t++) {
                float a  = __int_as_float(__builtin_amdgcn_readlane(__float_as_int(av[t]), k));
                float hh = __int_as_float(__builtin_amdgcn_readlane(__float_as_int(hv[t]), k));
                out[t] = fmaf(a, wr, out[t]);
                out[t] = fmaf(hh, wo, out[t]);
            }
        }
#pragma unroll
        for (int t = 0; t < TNODES; t++)
            hout[(size_t)(n0 + t) * HID + lane] = fmaxf(out[t], 0.0f);
    }
}

// ---------------- pooling (batch sorted): wave per 64-node chunk, atomics to ws ----------------

__global__ __launch_bounds__(256) void pool_kernel(
    const float* __restrict__ h, const int* __restrict__ batch,
    float* __restrict__ pooled_ws) {
    const int CH = 64;
    int lane = threadIdx.x & 63;
    int gwid = (blockIdx.x * blockDim.x + threadIdx.x) >> 6;
    int n0 = gwid * CH;
    if (n0 >= N_NODES) return;
    int nend = min(n0 + CH, N_NODES);
    int cur = batch[n0];
    float acc = 0.f;
    for (int n = n0; n < nend; n++) {
        int g = batch[n];
        if (g != cur) {
            atomicAdd(&pooled_ws[cur * HID + lane], acc);
            acc = 0.f;
            cur = g;
        }
        acc += h[(size_t)n * HID + lane];
    }
    atomicAdd(&pooled_ws[cur * HID + lane], acc);
}

// ---------------- MLP readout (also copies pooled -> d_out) ----------------

__global__ void mlp_kernel(const float* __restrict__ pooled_ws,
                           const float* __restrict__ W1, const float* __restrict__ b1,
                           const float* __restrict__ W2, const float* __restrict__ b2,
                           float* __restrict__ out, float* __restrict__ pooled_out) {
    __shared__ float sp[HID];
    __shared__ float red[4];
    int g = blockIdx.x, t = threadIdx.x;
    if (t < HID) {
        float v = pooled_ws[g * HID + t];
        sp[t] = v;
        pooled_out[g * HID + t] = v;
    }
    __syncthreads();
    float acc = b1[t];
#pragma unroll
    for (int k = 0; k < HID; k++) acc = fmaf(sp[k], W1[k * 128 + t], acc);
    float hid = fmaxf(acc, 0.f);
    float p0 = hid * W2[t * 2 + 0];
    float p1 = hid * W2[t * 2 + 1];
    for (int off = 32; off > 0; off >>= 1) {
        p0 += __shfl_down(p0, off, 64);
        p1 += __shfl_down(p1, off, 64);
    }
    int wave = t >> 6, lane = t & 63;
    if (lane == 0) { red[wave * 2 + 0] = p0; red[wave * 2 + 1] = p1; }
    __syncthreads();
    if (t == 0) {
        float o0 = red[0] + red[2] + b2[0];
        float o1 = red[1] + red[3] + b2[1];
        out[g * 2 + 0] = 1.f / (1.f + expf(-o0));
        out[g * 2 + 1] = 1.f / (1.f + expf(-o1));
    }
}

// ---------------- launcher ----------------

extern "C" void kernel_launch(void* const* d_in, const int* in_sizes, int n_in,
                              void* d_out, int out_size, void* d_ws, size_t ws_size,
                              hipStream_t stream) {
    const float* x      = (const float*)d_in[0];
    const int*   ei     = (const int*)d_in[1];
    const int*   batch  = (const int*)d_in[2];
    const float* W_rel  = (const float*)d_in[3];
    const float* W_root = (const float*)d_in[4];
    const float* b_conv = (const float*)d_in[5];
    const float* W1     = (const float*)d_in[6];
    const float* b1     = (const float*)d_in[7];
    const float* W2     = (const float*)d_in[8];
    const float* b2     = (const float*)d_in[9];

    float* outp       = (float*)d_out;                 // [512,2]
    float* pooled_out = (float*)d_out + N_GRAPHS * 2;  // [512,64]

    const size_t HROWS = (size_t)(N_NODES + 1) * HID;  // +1 zero dummy row

    char* ws = (char*)d_ws;
    size_t off = 0;
    float* hX = (float*)(ws + off); off += HROWS * 4;
    float* hA = (float*)(ws + off); off += HROWS * 4;
    float* hB = (float*)(ws + off); off += HROWS * 4;
    float* gg = (float*)(ws + off); off += (size_t)N_NODES * HID * 4;  // agg scratch
    int2* part    = (int2*)(ws + off); off += (size_t)N_EDGES * 8;     // 8B-aligned
    int* colidx   = (int*)(ws + off); off += (size_t)NBUCK * BSTRIDE * 4;
    int* row_ptr  = (int*)(ws + off); off += (size_t)(N_NODES + 4) * 4;
    int* pdeg     = (int*)(ws + off); off += (size_t)(N_NODES + 4) * 4;
    int* cbins    = (int*)(ws + off); off += (size_t)NBUCK * 4;
    int* cstart   = (int*)(ws + off); off += (size_t)(NBUCK + 1) * 4;
    int* ccursor  = (int*)(ws + off); off += (size_t)NBUCK * 4;
    float* pooled_ws = (float*)(ws + off); off += (size_t)N_GRAPHS * HID * 4;

    const int* esrc = ei;
    const int* edst = ei + N_EDGES;

    hipMemsetAsync(cbins, 0, (size_t)NBUCK * 4, stream);
    hipMemsetAsync(pooled_ws, 0, (size_t)N_GRAPHS * HID * 4, stream);
    // zero dummy rows (stay zero: transforms write only rows < N_NODES)
    hipMemsetAsync(hX + (size_t)N_NODES * HID, 0, HID * 4, stream);
    hipMemsetAsync(hA + (size_t)N_NODES * HID, 0, HID * 4, stream);
    hipMemsetAsync(hB + (size_t)N_NODES * HID, 0, HID * 4, stream);
    // layer-1 input with dummy row
    hipMemcpyAsync(hX, x, (size_t)N_NODES * HID * 4, hipMemcpyDeviceToDevice, stream);

    chist_kernel<<<NPBLK, 256, 0, stream>>>(edst, cbins);
    cscan_kernel<<<1, 1024, 0, stream>>>(cbins, cstart, ccursor);
    partition_kernel<<<NPBLK, 256, 0, stream>>>(esrc, edst, ccursor, part);
    bcsr_kernel<<<NBUCK, 256, 0, stream>>>(part, cstart, row_ptr, pdeg, colidx);

    // layer 1: hX -> hA
    gather_kernel<<<2048, 256, 0, stream>>>(hX, gg, row_ptr, pdeg, colidx);
    transform_kernel<<<3125, 256, 0, stream>>>(hX, gg, hA,
        W_rel + 0 * HID * HID, W_root + 0 * HID * HID, b_conv + 0 * HID);
    // layer 2: hA -> hB
    gather_kernel<<<2048, 256, 0, stream>>>(hA, gg, row_ptr, pdeg, colidx);
    transform_kernel<<<3125, 256, 0, stream>>>(hA, gg, hB,
        W_rel + 1 * HID * HID, W_root + 1 * HID * HID, b_conv + 1 * HID);
    // layer 3: hB -> hA
    gather_kernel<<<2048, 256, 0, stream>>>(hB, gg, row_ptr, pdeg, colidx);
    transform_kernel<<<3125, 256, 0, stream>>>(hB, gg, hA,
        W_rel + 2 * HID * HID, W_root + 2 * HID * HID, b_conv + 2 * HID);

    pool_kernel<<<391, 256, 0, stream>>>(hA, batch, pooled_ws);
    mlp_kernel<<<N_GRAPHS, 128, 0, stream>>>(pooled_ws, W1, b1, W2, b2, outp, pooled_out);
}

// Round 9
// 336.846 us; speedup vs baseline: 1.5553x; 1.5553x over previous
//
#include <hip/hip_runtime.h>
#include <math.h>

#define N_NODES 100000
#define N_EDGES 1600000
#define N_GRAPHS 512
#define HID 64
#define NC 3

#define NBUCK 782        // ceil(100000/128) buckets of 128 nodes
#define EPB 8192         // edges per block in chist/partition
#define NPBLK 196        // ceil(1600000/8192)
#define BSTRIDE 4096     // col entries reserved per bucket
#define DUMMY N_NODES    // padded col entries point at a zeroed row

typedef unsigned int uint;

__device__ __forceinline__ ushort f2bf(float f) {
    uint u = __float_as_uint(f);
    u += 0x7fffu + ((u >> 16) & 1u);   // RNE
    return (ushort)(u >> 16);
}
__device__ __forceinline__ uint packbf2(float a, float b) {
    return (uint)f2bf(a) | ((uint)f2bf(b) << 16);
}

// ---------------- CSR build, atomic-light 2-level counting sort (unchanged) ----------------

__global__ __launch_bounds__(256) void chist_kernel(const int* __restrict__ dst,
                                                    int* __restrict__ cbins) {
    __shared__ int bins[NBUCK];
    for (int i = threadIdx.x; i < NBUCK; i += 256) bins[i] = 0;
    __syncthreads();
    int start = blockIdx.x * EPB;
    int endd = min(start + EPB, N_EDGES);
    for (int e = start + threadIdx.x; e < endd; e += 256)
        atomicAdd(&bins[dst[e] >> 7], 1);
    __syncthreads();
    for (int i = threadIdx.x; i < NBUCK; i += 256)
        if (bins[i]) atomicAdd(&cbins[i], bins[i]);
}

__global__ __launch_bounds__(1024) void cscan_kernel(const int* __restrict__ cbins,
                                                     int* __restrict__ cstart,
                                                     int* __restrict__ ccursor) {
    __shared__ int s[1024];
    int t = threadIdx.x;
    int v = (t < NBUCK) ? cbins[t] : 0;
    int val = v;
    s[t] = val;
    __syncthreads();
    for (int off = 1; off < 1024; off <<= 1) {
        int o = (t >= off) ? s[t - off] : 0;
        __syncthreads();
        val += o;
        s[t] = val;
        __syncthreads();
    }
    if (t < NBUCK) {
        int ex = val - v;
        cstart[t] = ex;
        ccursor[t] = ex;
    }
    if (t == 0) cstart[NBUCK] = N_EDGES;
}

__global__ __launch_bounds__(256) void partition_kernel(const int* __restrict__ src,
                                                        const int* __restrict__ dst,
                                                        int* __restrict__ ccursor,
                                                        int2* __restrict__ part) {
    __shared__ int cnt[NBUCK];
    __shared__ int base[NBUCK];
    __shared__ int cur[NBUCK];
    for (int i = threadIdx.x; i < NBUCK; i += 256) { cnt[i] = 0; cur[i] = 0; }
    __syncthreads();
    int start = blockIdx.x * EPB;
    int endd = min(start + EPB, N_EDGES);
    for (int e = start + threadIdx.x; e < endd; e += 256)
        atomicAdd(&cnt[dst[e] >> 7], 1);
    __syncthreads();
    for (int i = threadIdx.x; i < NBUCK; i += 256)
        base[i] = cnt[i] ? atomicAdd(&ccursor[i], cnt[i]) : 0;
    __syncthreads();
    for (int e = start + threadIdx.x; e < endd; e += 256) {
        int d = dst[e];
        int b = d >> 7;
        int r = atomicAdd(&cur[b], 1);
        part[base[b] + r] = make_int2(src[e], d);
    }
}

__global__ __launch_bounds__(256) void bcsr_kernel(const int2* __restrict__ part,
                                                   const int* __restrict__ cstart,
                                                   int* __restrict__ row_ptr,
                                                   int* __restrict__ pdeg,
                                                   int* __restrict__ col) {
    __shared__ int deg[128];
    __shared__ int cur[128];
    __shared__ int pre[128];
    __shared__ int ss[256];
    int b = blockIdx.x;
    int t = threadIdx.x;
    int s0 = cstart[b], s1 = cstart[b + 1];
    if (t < 128) { deg[t] = 0; cur[t] = 0; }
    __syncthreads();
    for (int e = s0 + t; e < s1; e += 256)
        atomicAdd(&deg[part[e].y & 127], 1);
    __syncthreads();
    int v = (t < 128) ? ((deg[t] + 7) & ~7) : 0;  // degree padded to 8
    int val = v;
    ss[t] = val;
    __syncthreads();
    for (int off = 1; off < 256; off <<= 1) {
        int o = (t >= off) ? ss[t - off] : 0;
        __syncthreads();
        val += o;
        ss[t] = val;
        __syncthreads();
    }
    if (t < 128) pre[t] = val - v;
    __syncthreads();
    int base = b * BSTRIDE;
    int node = b * 128 + t;
    if (t < 128 && node < N_NODES) {
        row_ptr[node] = base + pre[t];
        pdeg[node] = v;
    }
    for (int e = s0 + t; e < s1; e += 256) {
        int2 p = part[e];
        int nl = p.y & 127;
        int r = atomicAdd(&cur[nl], 1);
        col[base + pre[nl] + r] = p.x;
    }
    __syncthreads();
    if (t < 128) {
        for (int i = deg[t]; i < v; i++)
            col[base + pre[t] + i] = DUMMY;
    }
}

// ---------------- x -> bf16 ----------------

__global__ __launch_bounds__(256) void cvt_kernel(const float* __restrict__ x,
                                                  ushort* __restrict__ hX) {
    int i = blockIdx.x * blockDim.x + threadIdx.x;
    int stride = gridDim.x * blockDim.x;
    const float4* x4 = (const float4*)x;
    for (; i < N_NODES * HID / 4; i += stride) {
        float4 v = x4[i];
        uint2 o;
        o.x = packbf2(v.x, v.y);
        o.y = packbf2(v.z, v.w);
        *(uint2*)(hX + (size_t)i * 4) = o;
    }
}

// ---------------- W transpose+bf16 prep: WT[layer][{rel,root}][col][k] ----------------

__global__ __launch_bounds__(256) void wprep_kernel(const float* __restrict__ W_rel,
                                                    const float* __restrict__ W_root,
                                                    ushort* __restrict__ WT) {
    int i = blockIdx.x * blockDim.x + threadIdx.x;
    if (i >= NC * 2 * HID * HID) return;
    int l = i / (2 * HID * HID);
    int rem = i % (2 * HID * HID);
    int m = rem / (HID * HID);
    int j = rem % (HID * HID);
    int colc = j / HID;
    int k = j % HID;
    const float* W = (m ? W_root : W_rel) + l * HID * HID;
    WT[i] = f2bf(W[k * HID + colc]);
}

// ---------------- gather (bf16 rows): agg[n] = sum hin[col[e]] ----------------
// Wave = 4 nodes x 16 lanes; lane covers 4 bf16 channels (8B). Rows padded to
// multiple of 8 -> unconditional 8-deep pipeline. fp32 accumulate, bf16 out.

#define ACC4(A, v) { A.x += __uint_as_float((v).x << 16); \
                     A.y += __uint_as_float((v).x & 0xffff0000u); \
                     A.z += __uint_as_float((v).y << 16); \
                     A.w += __uint_as_float((v).y & 0xffff0000u); }

__global__ __launch_bounds__(256) void gather_kernel(
    const ushort* __restrict__ hin, ushort* __restrict__ agg,
    const int* __restrict__ row_ptr, const int* __restrict__ pdeg,
    const int* __restrict__ col)
{
    int lane = threadIdx.x & 63;
    int slot = lane >> 4;
    int ch   = (lane & 15) * 4;
    int gwid = (blockIdx.x * blockDim.x + threadIdx.x) >> 6;
    int nwaves = (gridDim.x * blockDim.x) >> 6;

    for (int n0 = gwid * 4; n0 < N_NODES; n0 += nwaves * 4) {
        int n = n0 + slot;
        const int* row = col + row_ptr[n];
        int pd = pdeg[n];
        float4 a0 = {0.f,0.f,0.f,0.f}, a1 = {0.f,0.f,0.f,0.f};
        float4 a2 = {0.f,0.f,0.f,0.f}, a3 = {0.f,0.f,0.f,0.f};
        for (int e = 0; e < pd; e += 8) {
            int4 ca = *(const int4*)(row + e);
            int4 cb = *(const int4*)(row + e + 4);
            uint2 v0 = *(const uint2*)(hin + (size_t)ca.x * HID + ch);
            uint2 v1 = *(const uint2*)(hin + (size_t)ca.y * HID + ch);
            uint2 v2 = *(const uint2*)(hin + (size_t)ca.z * HID + ch);
            uint2 v3 = *(const uint2*)(hin + (size_t)ca.w * HID + ch);
            uint2 v4 = *(const uint2*)(hin + (size_t)cb.x * HID + ch);
            uint2 v5 = *(const uint2*)(hin + (size_t)cb.y * HID + ch);
            uint2 v6 = *(const uint2*)(hin + (size_t)cb.z * HID + ch);
            uint2 v7 = *(const uint2*)(hin + (size_t)cb.w * HID + ch);
            ACC4(a0, v0); ACC4(a1, v1); ACC4(a2, v2); ACC4(a3, v3);
            ACC4(a0, v4); ACC4(a1, v5); ACC4(a2, v6); ACC4(a3, v7);
        }
        a0.x += a1.x + a2.x + a3.x;
        a0.y += a1.y + a2.y + a3.y;
        a0.z += a1.z + a2.z + a3.z;
        a0.w += a1.w + a2.w + a3.w;
        uint2 o;
        o.x = packbf2(a0.x, a0.y);
        o.y = packbf2(a0.z, a0.w);
        *(uint2*)(agg + (size_t)n * HID + ch) = o;
    }
}

// ---------------- transform via MFMA: hout = relu(agg@Wrel + h@Wroot + b) ----------------
// Wave = 16 nodes x 64 out-ch. A frags from h/agg rows (lane&15 = node,
// lane>>4 = k-group of 8). B frags from WT (hoisted, loaded once).
// Epilogue through padded LDS for coalesced bf16 row stores.

__global__ __launch_bounds__(256) void transform_kernel(
    const ushort* __restrict__ hin, const ushort* __restrict__ agg,
    ushort* __restrict__ hout, const ushort* __restrict__ WTl,
    const float* __restrict__ bias)
{
    typedef __attribute__((ext_vector_type(8))) short short8;
    typedef __attribute__((ext_vector_type(4))) float f32x4;
    __shared__ float lds[4][16][68];
    int lane = threadIdx.x & 63;
    int wid  = threadIdx.x >> 6;
    int mrow = lane & 15;
    int kg   = lane >> 4;
    int gw = (blockIdx.x * blockDim.x + threadIdx.x) >> 6;
    int nw = (gridDim.x * blockDim.x) >> 6;

    short8 Bf[4][4];   // [col-tile][rel_h0, rel_h1, root_h0, root_h1]
#pragma unroll
    for (int c = 0; c < 4; c++)
#pragma unroll
        for (int m = 0; m < 2; m++)
#pragma unroll
            for (int h = 0; h < 2; h++)
                Bf[c][m * 2 + h] = *(const short8*)(
                    WTl + m * HID * HID + (c * 16 + mrow) * HID + h * 32 + kg * 8);

    float bv[4];
#pragma unroll
    for (int c = 0; c < 4; c++) bv[c] = bias[c * 16 + mrow];

    for (int ng = gw; ng < N_NODES / 16; ng += nw) {
        size_t rb = ((size_t)ng * 16 + mrow) * HID + kg * 8;
        short8 Ah0 = *(const short8*)(hin + rb);
        short8 Ah1 = *(const short8*)(hin + rb + 32);
        short8 Aa0 = *(const short8*)(agg + rb);
        short8 Aa1 = *(const short8*)(agg + rb + 32);
#pragma unroll
        for (int c = 0; c < 4; c++) {
            f32x4 acc = {0.f, 0.f, 0.f, 0.f};
            acc = __builtin_amdgcn_mfma_f32_16x16x32_bf16(Aa0, Bf[c][0], acc, 0, 0, 0);
            acc = __builtin_amdgcn_mfma_f32_16x16x32_bf16(Aa1, Bf[c][1], acc, 0, 0, 0);
            acc = __builtin_amdgcn_mfma_f32_16x16x32_bf16(Ah0, Bf[c][2], acc, 0, 0, 0);
            acc = __builtin_amdgcn_mfma_f32_16x16x32_bf16(Ah1, Bf[c][3], acc, 0, 0, 0);
#pragma unroll
            for (int r = 0; r < 4; r++)
                lds[wid][kg * 4 + r][c * 16 + mrow] = fmaxf(acc[r] + bv[c], 0.f);
        }
        asm volatile("s_waitcnt lgkmcnt(0)" ::: "memory");
        const float* lr = &lds[wid][mrow][kg * 16];
        float4 f0 = *(const float4*)(lr + 0);
        float4 f1 = *(const float4*)(lr + 4);
        float4 f2 = *(const float4*)(lr + 8);
        float4 f3 = *(const float4*)(lr + 12);
        uint4 o0, o1;
        o0.x = packbf2(f0.x, f0.y); o0.y = packbf2(f0.z, f0.w);
        o0.z = packbf2(f1.x, f1.y); o0.w = packbf2(f1.z, f1.w);
        o1.x = packbf2(f2.x, f2.y); o1.y = packbf2(f2.z, f2.w);
        o1.z = packbf2(f3.x, f3.y); o1.w = packbf2(f3.z, f3.w);
        ushort* orow = hout + ((size_t)ng * 16 + mrow) * HID + kg * 16;
        *(uint4*)(orow) = o0;
        *(uint4*)(orow + 8) = o1;
    }
}

// ---------------- pooling (batch sorted, bf16 h): wave per 64-node chunk ----------------

__global__ __launch_bounds__(256) void pool_kernel(
    const ushort* __restrict__ h, const int* __restrict__ batch,
    float* __restrict__ pooled_ws) {
    const int CH = 64;
    int lane = threadIdx.x & 63;
    int gwid = (blockIdx.x * blockDim.x + threadIdx.x) >> 6;
    int n0 = gwid * CH;
    if (n0 >= N_NODES) return;
    int nend = min(n0 + CH, N_NODES);
    int cur = batch[n0];
    float acc = 0.f;
    for (int n = n0; n < nend; n++) {
        int g = batch[n];
        if (g != cur) {
            atomicAdd(&pooled_ws[cur * HID + lane], acc);
            acc = 0.f;
            cur = g;
        }
        acc += __uint_as_float(((uint)h[(size_t)n * HID + lane]) << 16);
    }
    atomicAdd(&pooled_ws[cur * HID + lane], acc);
}

// ---------------- MLP readout (fp32, also copies pooled -> d_out) ----------------

__global__ void mlp_kernel(const float* __restrict__ pooled_ws,
                           const float* __restrict__ W1, const float* __restrict__ b1,
                           const float* __restrict__ W2, const float* __restrict__ b2,
                           float* __restrict__ out, float* __restrict__ pooled_out) {
    __shared__ float sp[HID];
    __shared__ float red[4];
    int g = blockIdx.x, t = threadIdx.x;
    if (t < HID) {
        float v = pooled_ws[g * HID + t];
        sp[t] = v;
        pooled_out[g * HID + t] = v;
    }
    __syncthreads();
    float acc = b1[t];
#pragma unroll
    for (int k = 0; k < HID; k++) acc = fmaf(sp[k], W1[k * 128 + t], acc);
    float hid = fmaxf(acc, 0.f);
    float p0 = hid * W2[t * 2 + 0];
    float p1 = hid * W2[t * 2 + 1];
    for (int off = 32; off > 0; off >>= 1) {
        p0 += __shfl_down(p0, off, 64);
        p1 += __shfl_down(p1, off, 64);
    }
    int wave = t >> 6, lane = t & 63;
    if (lane == 0) { red[wave * 2 + 0] = p0; red[wave * 2 + 1] = p1; }
    __syncthreads();
    if (t == 0) {
        float o0 = red[0] + red[2] + b2[0];
        float o1 = red[1] + red[3] + b2[1];
        out[g * 2 + 0] = 1.f / (1.f + expf(-o0));
        out[g * 2 + 1] = 1.f / (1.f + expf(-o1));
    }
}

// ---------------- launcher ----------------

extern "C" void kernel_launch(void* const* d_in, const int* in_sizes, int n_in,
                              void* d_out, int out_size, void* d_ws, size_t ws_size,
                              hipStream_t stream) {
    const float* x      = (const float*)d_in[0];
    const int*   ei     = (const int*)d_in[1];
    const int*   batch  = (const int*)d_in[2];
    const float* W_rel  = (const float*)d_in[3];
    const float* W_root = (const float*)d_in[4];
    const float* b_conv = (const float*)d_in[5];
    const float* W1     = (const float*)d_in[6];
    const float* b1     = (const float*)d_in[7];
    const float* W2     = (const float*)d_in[8];
    const float* b2     = (const float*)d_in[9];

    float* outp       = (float*)d_out;                 // [512,2]
    float* pooled_out = (float*)d_out + N_GRAPHS * 2;  // [512,64]

    const size_t HROWS_B = ((size_t)(N_NODES + 1) * HID * 2 + 255) & ~(size_t)255;

    char* ws = (char*)d_ws;
    size_t off = 0;
    ushort* hX = (ushort*)(ws + off); off += HROWS_B;
    ushort* hA = (ushort*)(ws + off); off += HROWS_B;
    ushort* hB = (ushort*)(ws + off); off += HROWS_B;
    ushort* gg = (ushort*)(ws + off); off += ((size_t)N_NODES * HID * 2 + 255) & ~(size_t)255;
    ushort* WT = (ushort*)(ws + off); off += ((size_t)NC * 2 * HID * HID * 2 + 255) & ~(size_t)255;
    int2* part    = (int2*)(ws + off); off += (size_t)N_EDGES * 8;
    int* colidx   = (int*)(ws + off); off += (size_t)NBUCK * BSTRIDE * 4;
    int* row_ptr  = (int*)(ws + off); off += (size_t)(N_NODES + 4) * 4;
    int* pdeg     = (int*)(ws + off); off += (size_t)(N_NODES + 4) * 4;
    int* cbins    = (int*)(ws + off); off += (size_t)NBUCK * 4;
    int* cstart   = (int*)(ws + off); off += (size_t)(NBUCK + 4) * 4;
    int* ccursor  = (int*)(ws + off); off += (size_t)NBUCK * 4;
    float* pooled_ws = (float*)(ws + off); off += (size_t)N_GRAPHS * HID * 4;

    const int* esrc = ei;
    const int* edst = ei + N_EDGES;

    hipMemsetAsync(cbins, 0, (size_t)NBUCK * 4, stream);
    hipMemsetAsync(pooled_ws, 0, (size_t)N_GRAPHS * HID * 4, stream);
    // zero dummy rows (transform/cvt write only rows < N_NODES)
    hipMemsetAsync(hX + (size_t)N_NODES * HID, 0, HID * 2, stream);
    hipMemsetAsync(hA + (size_t)N_NODES * HID, 0, HID * 2, stream);
    hipMemsetAsync(hB + (size_t)N_NODES * HID, 0, HID * 2, stream);

    cvt_kernel<<<2048, 256, 0, stream>>>(x, hX);
    wprep_kernel<<<(NC * 2 * HID * HID + 255) / 256, 256, 0, stream>>>(W_rel, W_root, WT);

    chist_kernel<<<NPBLK, 256, 0, stream>>>(edst, cbins);
    cscan_kernel<<<1, 1024, 0, stream>>>(cbins, cstart, ccursor);
    partition_kernel<<<NPBLK, 256, 0, stream>>>(esrc, edst, ccursor, part);
    bcsr_kernel<<<NBUCK, 256, 0, stream>>>(part, cstart, row_ptr, pdeg, colidx);

    // layer 1: hX -> hA
    gather_kernel<<<2048, 256, 0, stream>>>(hX, gg, row_ptr, pdeg, colidx);
    transform_kernel<<<512, 256, 0, stream>>>(hX, gg, hA, WT + 0 * 2 * HID * HID, b_conv + 0 * HID);
    // layer 2: hA -> hB
    gather_kernel<<<2048, 256, 0, stream>>>(hA, gg, row_ptr, pdeg, colidx);
    transform_kernel<<<512, 256, 0, stream>>>(hA, gg, hB, WT + 1 * 2 * HID * HID, b_conv + 1 * HID);
    // layer 3: hB -> hA
    gather_kernel<<<2048, 256, 0, stream>>>(hB, gg, row_ptr, pdeg, colidx);
    transform_kernel<<<512, 256, 0, stream>>>(hB, gg, hA, WT + 2 * 2 * HID * HID, b_conv + 2 * HID);

    pool_kernel<<<391, 256, 0, stream>>>(hA, batch, pooled_ws);
    mlp_kernel<<<N_GRAPHS, 128, 0, stream>>>(pooled_ws, W1, b1, W2, b2, outp, pooled_out);
}

// Round 10
// 306.111 us; speedup vs baseline: 1.7115x; 1.1004x over previous
//
#include <hip/hip_runtime.h>
#include <math.h>

#define N_NODES 100000
#define N_EDGES 1600000
#define N_GRAPHS 512
#define HID 64
#define NC 3

#define NBUCK 782        // ceil(100000/128) buckets of 128 nodes
#define EPB 4096         // edges per block in partition
#define NPBLK 391        // ceil(1600000/4096)
#define PSTRIDE 3072     // part entries reserved per bucket (mean 2048, sigma 45 -> 22 sigma)
#define BSTRIDE 4096     // col entries reserved per bucket
#define DUMMY N_NODES    // padded col entries point at a zeroed row

typedef unsigned int uint;

__device__ __forceinline__ ushort f2bf(float f) {
    uint u = __float_as_uint(f);
    u += 0x7fffu + ((u >> 16) & 1u);   // RNE
    return (ushort)(u >> 16);
}
__device__ __forceinline__ uint packbf2(float a, float b) {
    return (uint)f2bf(a) | ((uint)f2bf(b) << 16);
}

// ---------------- partition: edges -> fixed per-bucket regions (no scan needed) ----------------

__global__ __launch_bounds__(256) void partition_kernel(const int* __restrict__ src,
                                                        const int* __restrict__ dst,
                                                        int* __restrict__ ccursor,
                                                        int2* __restrict__ part) {
    __shared__ int cnt[NBUCK];
    __shared__ int base[NBUCK];
    __shared__ int cur[NBUCK];
    for (int i = threadIdx.x; i < NBUCK; i += 256) { cnt[i] = 0; cur[i] = 0; }
    __syncthreads();
    const int4* d4 = (const int4*)dst;
    const int4* s4 = (const int4*)src;
    int i0 = blockIdx.x * (EPB / 4);
    int i1 = min(i0 + EPB / 4, N_EDGES / 4);
    for (int i = i0 + threadIdx.x; i < i1; i += 256) {
        int4 d = d4[i];
        atomicAdd(&cnt[d.x >> 7], 1);
        atomicAdd(&cnt[d.y >> 7], 1);
        atomicAdd(&cnt[d.z >> 7], 1);
        atomicAdd(&cnt[d.w >> 7], 1);
    }
    __syncthreads();
    for (int i = threadIdx.x; i < NBUCK; i += 256)
        base[i] = cnt[i] ? (i * PSTRIDE + atomicAdd(&ccursor[i], cnt[i])) : 0;
    __syncthreads();
    for (int i = i0 + threadIdx.x; i < i1; i += 256) {
        int4 d = d4[i];
        int4 s = s4[i];
        int b0 = d.x >> 7; part[base[b0] + atomicAdd(&cur[b0], 1)] = make_int2(s.x, d.x);
        int b1 = d.y >> 7; part[base[b1] + atomicAdd(&cur[b1], 1)] = make_int2(s.y, d.y);
        int b2 = d.z >> 7; part[base[b2] + atomicAdd(&cur[b2], 1)] = make_int2(s.z, d.z);
        int b3 = d.w >> 7; part[base[b3] + atomicAdd(&cur[b3], 1)] = make_int2(s.w, d.w);
    }
}

// Per bucket: LDS histogram of its 128 nodes, padded-to-8 prefix scan, ranked
// placement into col[bucket*BSTRIDE ...], pad slots filled with DUMMY.

__global__ __launch_bounds__(256) void bcsr_kernel(const int2* __restrict__ part,
                                                   const int* __restrict__ ccursor,
                                                   int* __restrict__ row_ptr,
                                                   int* __restrict__ pdeg,
                                                   int* __restrict__ col) {
    __shared__ int deg[128];
    __shared__ int cur[128];
    __shared__ int pre[128];
    __shared__ int ss[256];
    int b = blockIdx.x;
    int t = threadIdx.x;
    int s0 = b * PSTRIDE;
    int s1 = s0 + ccursor[b];
    if (t < 128) { deg[t] = 0; cur[t] = 0; }
    __syncthreads();
    for (int e = s0 + t; e < s1; e += 256)
        atomicAdd(&deg[part[e].y & 127], 1);
    __syncthreads();
    int v = (t < 128) ? ((deg[t] + 7) & ~7) : 0;  // degree padded to 8
    int val = v;
    ss[t] = val;
    __syncthreads();
    for (int off = 1; off < 256; off <<= 1) {
        int o = (t >= off) ? ss[t - off] : 0;
        __syncthreads();
        val += o;
        ss[t] = val;
        __syncthreads();
    }
    if (t < 128) pre[t] = val - v;
    __syncthreads();
    int base = b * BSTRIDE;
    int node = b * 128 + t;
    if (t < 128 && node < N_NODES) {
        row_ptr[node] = base + pre[t];
        pdeg[node] = v;
    }
    for (int e = s0 + t; e < s1; e += 256) {
        int2 p = part[e];
        int nl = p.y & 127;
        int r = atomicAdd(&cur[nl], 1);
        col[base + pre[nl] + r] = p.x;
    }
    __syncthreads();
    if (t < 128) {
        for (int i = deg[t]; i < v; i++)
            col[base + pre[t] + i] = DUMMY;
    }
}

// ---------------- x -> bf16 ----------------

__global__ __launch_bounds__(256) void cvt_kernel(const float* __restrict__ x,
                                                  ushort* __restrict__ hX) {
    int i = blockIdx.x * blockDim.x + threadIdx.x;
    int stride = gridDim.x * blockDim.x;
    const float4* x4 = (const float4*)x;
    for (; i < N_NODES * HID / 4; i += stride) {
        float4 v = x4[i];
        uint2 o;
        o.x = packbf2(v.x, v.y);
        o.y = packbf2(v.z, v.w);
        *(uint2*)(hX + (size_t)i * 4) = o;
    }
}

// ---------------- W transpose+bf16 prep: WT[layer][{rel,root}][col][k] ----------------

__global__ __launch_bounds__(256) void wprep_kernel(const float* __restrict__ W_rel,
                                                    const float* __restrict__ W_root,
                                                    ushort* __restrict__ WT) {
    int i = blockIdx.x * blockDim.x + threadIdx.x;
    if (i >= NC * 2 * HID * HID) return;
    int l = i / (2 * HID * HID);
    int rem = i % (2 * HID * HID);
    int m = rem / (HID * HID);
    int j = rem % (HID * HID);
    int colc = j / HID;
    int k = j % HID;
    const float* W = (m ? W_root : W_rel) + l * HID * HID;
    WT[i] = f2bf(W[k * HID + colc]);
}

// ---------------- gather (bf16 rows): agg[n] = sum hin[col[e]] ----------------
// Wave = 4 nodes x 16 lanes; lane covers 4 bf16 channels (8B). Rows padded to
// multiple of 8 -> unconditional 8-deep pipeline. fp32 accumulate, bf16 out.

#define ACC4(A, v) { A.x += __uint_as_float((v).x << 16); \
                     A.y += __uint_as_float((v).x & 0xffff0000u); \
                     A.z += __uint_as_float((v).y << 16); \
                     A.w += __uint_as_float((v).y & 0xffff0000u); }

__global__ __launch_bounds__(256) void gather_kernel(
    const ushort* __restrict__ hin, ushort* __restrict__ agg,
    const int* __restrict__ row_ptr, const int* __restrict__ pdeg,
    const int* __restrict__ col)
{
    int lane = threadIdx.x & 63;
    int slot = lane >> 4;
    int ch   = (lane & 15) * 4;
    int gwid = (blockIdx.x * blockDim.x + threadIdx.x) >> 6;
    int nwaves = (gridDim.x * blockDim.x) >> 6;

    for (int n0 = gwid * 4; n0 < N_NODES; n0 += nwaves * 4) {
        int n = n0 + slot;
        const int* row = col + row_ptr[n];
        int pd = pdeg[n];
        float4 a0 = {0.f,0.f,0.f,0.f}, a1 = {0.f,0.f,0.f,0.f};
        float4 a2 = {0.f,0.f,0.f,0.f}, a3 = {0.f,0.f,0.f,0.f};
        for (int e = 0; e < pd; e += 8) {
            int4 ca = *(const int4*)(row + e);
            int4 cb = *(const int4*)(row + e + 4);
            uint2 v0 = *(const uint2*)(hin + (size_t)ca.x * HID + ch);
            uint2 v1 = *(const uint2*)(hin + (size_t)ca.y * HID + ch);
            uint2 v2 = *(const uint2*)(hin + (size_t)ca.z * HID + ch);
            uint2 v3 = *(const uint2*)(hin + (size_t)ca.w * HID + ch);
            uint2 v4 = *(const uint2*)(hin + (size_t)cb.x * HID + ch);
            uint2 v5 = *(const uint2*)(hin + (size_t)cb.y * HID + ch);
            uint2 v6 = *(const uint2*)(hin + (size_t)cb.z * HID + ch);
            uint2 v7 = *(const uint2*)(hin + (size_t)cb.w * HID + ch);
            ACC4(a0, v0); ACC4(a1, v1); ACC4(a2, v2); ACC4(a3, v3);
            ACC4(a0, v4); ACC4(a1, v5); ACC4(a2, v6); ACC4(a3, v7);
        }
        a0.x += a1.x + a2.x + a3.x;
        a0.y += a1.y + a2.y + a3.y;
        a0.z += a1.z + a2.z + a3.z;
        a0.w += a1.w + a2.w + a3.w;
        uint2 o;
        o.x = packbf2(a0.x, a0.y);
        o.y = packbf2(a0.z, a0.w);
        *(uint2*)(agg + (size_t)n * HID + ch) = o;
    }
}

// ---------------- transform via MFMA: hout = relu(agg@Wrel + h@Wroot + b) ----------------
// Wave = 16 nodes x 64 out-ch. A frags from h/agg rows (lane&15 = node,
// lane>>4 = k-group of 8). B frags from WT (hoisted, loaded once).
// Epilogue through padded LDS for coalesced bf16 row stores.

__global__ __launch_bounds__(256) void transform_kernel(
    const ushort* __restrict__ hin, const ushort* __restrict__ agg,
    ushort* __restrict__ hout, const ushort* __restrict__ WTl,
    const float* __restrict__ bias)
{
    typedef __attribute__((ext_vector_type(8))) short short8;
    typedef __attribute__((ext_vector_type(4))) float f32x4;
    __shared__ float lds[4][16][68];
    int lane = threadIdx.x & 63;
    int wid  = threadIdx.x >> 6;
    int mrow = lane & 15;
    int kg   = lane >> 4;
    int gw = (blockIdx.x * blockDim.x + threadIdx.x) >> 6;
    int nw = (gridDim.x * blockDim.x) >> 6;

    short8 Bf[4][4];   // [col-tile][rel_h0, rel_h1, root_h0, root_h1]
#pragma unroll
    for (int c = 0; c < 4; c++)
#pragma unroll
        for (int m = 0; m < 2; m++)
#pragma unroll
            for (int h = 0; h < 2; h++)
                Bf[c][m * 2 + h] = *(const short8*)(
                    WTl + m * HID * HID + (c * 16 + mrow) * HID + h * 32 + kg * 8);

    float bv[4];
#pragma unroll
    for (int c = 0; c < 4; c++) bv[c] = bias[c * 16 + mrow];

    for (int ng = gw; ng < N_NODES / 16; ng += nw) {
        size_t rb = ((size_t)ng * 16 + mrow) * HID + kg * 8;
        short8 Ah0 = *(const short8*)(hin + rb);
        short8 Ah1 = *(const short8*)(hin + rb + 32);
        short8 Aa0 = *(const short8*)(agg + rb);
        short8 Aa1 = *(const short8*)(agg + rb + 32);
#pragma unroll
        for (int c = 0; c < 4; c++) {
            f32x4 acc = {0.f, 0.f, 0.f, 0.f};
            acc = __builtin_amdgcn_mfma_f32_16x16x32_bf16(Aa0, Bf[c][0], acc, 0, 0, 0);
            acc = __builtin_amdgcn_mfma_f32_16x16x32_bf16(Aa1, Bf[c][1], acc, 0, 0, 0);
            acc = __builtin_amdgcn_mfma_f32_16x16x32_bf16(Ah0, Bf[c][2], acc, 0, 0, 0);
            acc = __builtin_amdgcn_mfma_f32_16x16x32_bf16(Ah1, Bf[c][3], acc, 0, 0, 0);
#pragma unroll
            for (int r = 0; r < 4; r++)
                lds[wid][kg * 4 + r][c * 16 + mrow] = fmaxf(acc[r] + bv[c], 0.f);
        }
        asm volatile("s_waitcnt lgkmcnt(0)" ::: "memory");
        const float* lr = &lds[wid][mrow][kg * 16];
        float4 f0 = *(const float4*)(lr + 0);
        float4 f1 = *(const float4*)(lr + 4);
        float4 f2 = *(const float4*)(lr + 8);
        float4 f3 = *(const float4*)(lr + 12);
        uint4 o0, o1;
        o0.x = packbf2(f0.x, f0.y); o0.y = packbf2(f0.z, f0.w);
        o0.z = packbf2(f1.x, f1.y); o0.w = packbf2(f1.z, f1.w);
        o1.x = packbf2(f2.x, f2.y); o1.y = packbf2(f2.z, f2.w);
        o1.z = packbf2(f3.x, f3.y); o1.w = packbf2(f3.z, f3.w);
        ushort* orow = hout + ((size_t)ng * 16 + mrow) * HID + kg * 16;
        *(uint4*)(orow) = o0;
        *(uint4*)(orow + 8) = o1;
    }
}

// ---------------- pooling (batch sorted, bf16 h): wave per 64-node chunk ----------------

__global__ __launch_bounds__(256) void pool_kernel(
    const ushort* __restrict__ h, const int* __restrict__ batch,
    float* __restrict__ pooled_ws) {
    const int CH = 64;
    int lane = threadIdx.x & 63;
    int gwid = (blockIdx.x * blockDim.x + threadIdx.x) >> 6;
    int n0 = gwid * CH;
    if (n0 >= N_NODES) return;
    int nend = min(n0 + CH, N_NODES);
    int cur = batch[n0];
    float acc = 0.f;
    for (int n = n0; n < nend; n++) {
        int g = batch[n];
        if (g != cur) {
            atomicAdd(&pooled_ws[cur * HID + lane], acc);
            acc = 0.f;
            cur = g;
        }
        acc += __uint_as_float(((uint)h[(size_t)n * HID + lane]) << 16);
    }
    atomicAdd(&pooled_ws[cur * HID + lane], acc);
}

// ---------------- MLP readout (fp32, also copies pooled -> d_out) ----------------

__global__ void mlp_kernel(const float* __restrict__ pooled_ws,
                           const float* __restrict__ W1, const float* __restrict__ b1,
                           const float* __restrict__ W2, const float* __restrict__ b2,
                           float* __restrict__ out, float* __restrict__ pooled_out) {
    __shared__ float sp[HID];
    __shared__ float red[4];
    int g = blockIdx.x, t = threadIdx.x;
    if (t < HID) {
        float v = pooled_ws[g * HID + t];
        sp[t] = v;
        pooled_out[g * HID + t] = v;
    }
    __syncthreads();
    float acc = b1[t];
#pragma unroll
    for (int k = 0; k < HID; k++) acc = fmaf(sp[k], W1[k * 128 + t], acc);
    float hid = fmaxf(acc, 0.f);
    float p0 = hid * W2[t * 2 + 0];
    float p1 = hid * W2[t * 2 + 1];
    for (int off = 32; off > 0; off >>= 1) {
        p0 += __shfl_down(p0, off, 64);
        p1 += __shfl_down(p1, off, 64);
    }
    int wave = t >> 6, lane = t & 63;
    if (lane == 0) { red[wave * 2 + 0] = p0; red[wave * 2 + 1] = p1; }
    __syncthreads();
    if (t == 0) {
        float o0 = red[0] + red[2] + b2[0];
        float o1 = red[1] + red[3] + b2[1];
        out[g * 2 + 0] = 1.f / (1.f + expf(-o0));
        out[g * 2 + 1] = 1.f / (1.f + expf(-o1));
    }
}

// ---------------- launcher ----------------

extern "C" void kernel_launch(void* const* d_in, const int* in_sizes, int n_in,
                              void* d_out, int out_size, void* d_ws, size_t ws_size,
                              hipStream_t stream) {
    const float* x      = (const float*)d_in[0];
    const int*   ei     = (const int*)d_in[1];
    const int*   batch  = (const int*)d_in[2];
    const float* W_rel  = (const float*)d_in[3];
    const float* W_root = (const float*)d_in[4];
    const float* b_conv = (const float*)d_in[5];
    const float* W1     = (const float*)d_in[6];
    const float* b1     = (const float*)d_in[7];
    const float* W2     = (const float*)d_in[8];
    const float* b2     = (const float*)d_in[9];

    float* outp       = (float*)d_out;                 // [512,2]
    float* pooled_out = (float*)d_out + N_GRAPHS * 2;  // [512,64]

    const size_t HROWS_B = ((size_t)(N_NODES + 1) * HID * 2 + 255) & ~(size_t)255;

    char* ws = (char*)d_ws;
    size_t off = 0;
    ushort* hX = (ushort*)(ws + off); off += HROWS_B;
    ushort* hA = (ushort*)(ws + off); off += HROWS_B;
    ushort* hB = (ushort*)(ws + off); off += HROWS_B;
    ushort* gg = (ushort*)(ws + off); off += ((size_t)N_NODES * HID * 2 + 255) & ~(size_t)255;
    ushort* WT = (ushort*)(ws + off); off += ((size_t)NC * 2 * HID * HID * 2 + 255) & ~(size_t)255;
    int2* part    = (int2*)(ws + off); off += (size_t)NBUCK * PSTRIDE * 8;
    int* colidx   = (int*)(ws + off); off += (size_t)NBUCK * BSTRIDE * 4;
    int* row_ptr  = (int*)(ws + off); off += (size_t)(N_NODES + 4) * 4;
    int* pdeg     = (int*)(ws + off); off += (size_t)(N_NODES + 4) * 4;
    int* ccursor  = (int*)(ws + off); off += (size_t)NBUCK * 4;
    float* pooled_ws = (float*)(ws + off); off += (size_t)N_GRAPHS * HID * 4;

    const int* esrc = ei;
    const int* edst = ei + N_EDGES;

    hipMemsetAsync(ccursor, 0, (size_t)NBUCK * 4, stream);
    hipMemsetAsync(pooled_ws, 0, (size_t)N_GRAPHS * HID * 4, stream);
    // zero dummy rows (transform/cvt write only rows < N_NODES)
    hipMemsetAsync(hX + (size_t)N_NODES * HID, 0, HID * 2, stream);
    hipMemsetAsync(hA + (size_t)N_NODES * HID, 0, HID * 2, stream);
    hipMemsetAsync(hB + (size_t)N_NODES * HID, 0, HID * 2, stream);

    cvt_kernel<<<2048, 256, 0, stream>>>(x, hX);
    wprep_kernel<<<(NC * 2 * HID * HID + 255) / 256, 256, 0, stream>>>(W_rel, W_root, WT);

    partition_kernel<<<NPBLK, 256, 0, stream>>>(esrc, edst, ccursor, part);
    bcsr_kernel<<<NBUCK, 256, 0, stream>>>(part, ccursor, row_ptr, pdeg, colidx);

    // layer 1: hX -> hA
    gather_kernel<<<2048, 256, 0, stream>>>(hX, gg, row_ptr, pdeg, colidx);
    transform_kernel<<<512, 256, 0, stream>>>(hX, gg, hA, WT + 0 * 2 * HID * HID, b_conv + 0 * HID);
    // layer 2: hA -> hB
    gather_kernel<<<2048, 256, 0, stream>>>(hA, gg, row_ptr, pdeg, colidx);
    transform_kernel<<<512, 256, 0, stream>>>(hA, gg, hB, WT + 1 * 2 * HID * HID, b_conv + 1 * HID);
    // layer 3: hB -> hA
    gather_kernel<<<2048, 256, 0, stream>>>(hB, gg, row_ptr, pdeg, colidx);
    transform_kernel<<<512, 256, 0, stream>>>(hB, gg, hA, WT + 2 * 2 * HID * HID, b_conv + 2 * HID);

    pool_kernel<<<391, 256, 0, stream>>>(hA, batch, pooled_ws);
    mlp_kernel<<<N_GRAPHS, 128, 0, stream>>>(pooled_ws, W1, b1, W2, b2, outp, pooled_out);
}

// Round 11
// 290.458 us; speedup vs baseline: 1.8037x; 1.0539x over previous
//
#include <hip/hip_runtime.h>
#include <math.h>

#define N_NODES 100000
#define N_EDGES 1600000
#define N_GRAPHS 512
#define HID 64
#define NC 3

#define NBUCK 782        // ceil(100000/128) buckets of 128 nodes
#define EPB 8192         // edges per block in partition
#define NPBLK 196        // ceil(1600000/8192)
#define PSTRIDE 3072     // part entries reserved per bucket (mean 2048, sigma 45)
#define BSTRIDE 4096     // col entries reserved per bucket
#define DUMMY N_NODES    // padded col entries point at a zeroed row
#define SRCMASK 0x1FFFF  // 17 bits: N_NODES < 131072

typedef unsigned int uint;

__device__ __forceinline__ ushort f2bf(float f) {
    uint u = __float_as_uint(f);
    u += 0x7fffu + ((u >> 16) & 1u);   // RNE
    return (ushort)(u >> 16);
}
__device__ __forceinline__ uint packbf2(float a, float b) {
    return (uint)f2bf(a) | ((uint)f2bf(b) << 16);
}

// ---------------- partition: edges -> fixed per-bucket regions, packed 4B entries ----------------
// entry = (dst&127)<<17 | src. 196 blocks x 512 threads; fewer blocks => longer
// per-(block,bucket) runs => fewer write-allocate line RFOs.

__global__ __launch_bounds__(512) void partition_kernel(const int* __restrict__ src,
                                                        const int* __restrict__ dst,
                                                        int* __restrict__ ccursor,
                                                        uint* __restrict__ part) {
    __shared__ int cnt[NBUCK];
    __shared__ int base[NBUCK];
    __shared__ int cur[NBUCK];
    for (int i = threadIdx.x; i < NBUCK; i += 512) { cnt[i] = 0; cur[i] = 0; }
    __syncthreads();
    const int4* d4 = (const int4*)dst;
    const int4* s4 = (const int4*)src;
    int i0 = blockIdx.x * (EPB / 4);
    int i1 = min(i0 + EPB / 4, N_EDGES / 4);
    for (int i = i0 + threadIdx.x; i < i1; i += 512) {
        int4 d = d4[i];
        atomicAdd(&cnt[d.x >> 7], 1);
        atomicAdd(&cnt[d.y >> 7], 1);
        atomicAdd(&cnt[d.z >> 7], 1);
        atomicAdd(&cnt[d.w >> 7], 1);
    }
    __syncthreads();
    for (int i = threadIdx.x; i < NBUCK; i += 512)
        base[i] = cnt[i] ? (i * PSTRIDE + atomicAdd(&ccursor[i], cnt[i])) : 0;
    __syncthreads();
    for (int i = i0 + threadIdx.x; i < i1; i += 512) {
        int4 d = d4[i];
        int4 s = s4[i];
        int b0 = d.x >> 7; part[base[b0] + atomicAdd(&cur[b0], 1)] = ((uint)(d.x & 127) << 17) | (uint)s.x;
        int b1 = d.y >> 7; part[base[b1] + atomicAdd(&cur[b1], 1)] = ((uint)(d.y & 127) << 17) | (uint)s.y;
        int b2 = d.z >> 7; part[base[b2] + atomicAdd(&cur[b2], 1)] = ((uint)(d.z & 127) << 17) | (uint)s.z;
        int b3 = d.w >> 7; part[base[b3] + atomicAdd(&cur[b3], 1)] = ((uint)(d.w & 127) << 17) | (uint)s.w;
    }
}

// Per bucket: LDS histogram of its 128 nodes, padded-to-8 prefix scan, ranked
// placement into col[bucket*BSTRIDE ...], pad slots filled with DUMMY.

__global__ __launch_bounds__(256) void bcsr_kernel(const uint* __restrict__ part,
                                                   const int* __restrict__ ccursor,
                                                   int* __restrict__ row_ptr,
                                                   int* __restrict__ pdeg,
                                                   int* __restrict__ col) {
    __shared__ int deg[128];
    __shared__ int cur[128];
    __shared__ int pre[128];
    __shared__ int ss[256];
    int b = blockIdx.x;
    int t = threadIdx.x;
    int s0 = b * PSTRIDE;
    int s1 = s0 + ccursor[b];
    if (t < 128) { deg[t] = 0; cur[t] = 0; }
    __syncthreads();
    for (int e = s0 + t; e < s1; e += 256)
        atomicAdd(&deg[part[e] >> 17], 1);
    __syncthreads();
    int v = (t < 128) ? ((deg[t] + 7) & ~7) : 0;  // degree padded to 8
    int val = v;
    ss[t] = val;
    __syncthreads();
    for (int off = 1; off < 256; off <<= 1) {
        int o = (t >= off) ? ss[t - off] : 0;
        __syncthreads();
        val += o;
        ss[t] = val;
        __syncthreads();
    }
    if (t < 128) pre[t] = val - v;
    __syncthreads();
    int base = b * BSTRIDE;
    int node = b * 128 + t;
    if (t < 128 && node < N_NODES) {
        row_ptr[node] = base + pre[t];
        pdeg[node] = v;
    }
    for (int e = s0 + t; e < s1; e += 256) {
        uint p = part[e];
        int nl = p >> 17;
        int r = atomicAdd(&cur[nl], 1);
        col[base + pre[nl] + r] = (int)(p & SRCMASK);
    }
    __syncthreads();
    if (t < 128) {
        for (int i = deg[t]; i < v; i++)
            col[base + pre[t] + i] = DUMMY;
    }
}

// ---------------- x -> bf16 (+ zero the dummy rows of hX/hA/hB) ----------------

__global__ __launch_bounds__(256) void cvt_kernel(const float* __restrict__ x,
                                                  ushort* __restrict__ hX,
                                                  ushort* __restrict__ hA,
                                                  ushort* __restrict__ hB) {
    if (blockIdx.x == 0 && threadIdx.x < HID) {
        hX[(size_t)N_NODES * HID + threadIdx.x] = 0;
        hA[(size_t)N_NODES * HID + threadIdx.x] = 0;
        hB[(size_t)N_NODES * HID + threadIdx.x] = 0;
    }
    int i = blockIdx.x * blockDim.x + threadIdx.x;
    int stride = gridDim.x * blockDim.x;
    const float4* x4 = (const float4*)x;
    for (; i < N_NODES * HID / 4; i += stride) {
        float4 v = x4[i];
        uint2 o;
        o.x = packbf2(v.x, v.y);
        o.y = packbf2(v.z, v.w);
        *(uint2*)(hX + (size_t)i * 4) = o;
    }
}

// ---------------- W transpose+bf16 prep: WT[layer][{rel,root}][col][k] ----------------

__global__ __launch_bounds__(256) void wprep_kernel(const float* __restrict__ W_rel,
                                                    const float* __restrict__ W_root,
                                                    ushort* __restrict__ WT) {
    int i = blockIdx.x * blockDim.x + threadIdx.x;
    if (i >= NC * 2 * HID * HID) return;
    int l = i / (2 * HID * HID);
    int rem = i % (2 * HID * HID);
    int m = rem / (HID * HID);
    int j = rem % (HID * HID);
    int colc = j / HID;
    int k = j % HID;
    const float* W = (m ? W_root : W_rel) + l * HID * HID;
    WT[i] = f2bf(W[k * HID + colc]);
}

// ---------------- gather (bf16 rows): agg[n] = sum hin[col[e]] ----------------
// Wave = 4 nodes x 16 lanes; lane covers 4 bf16 channels (8B). Rows padded to
// multiple of 8 -> unconditional 8-deep pipeline. fp32 accumulate, bf16 out.

#define ACC4(A, v) { A.x += __uint_as_float((v).x << 16); \
                     A.y += __uint_as_float((v).x & 0xffff0000u); \
                     A.z += __uint_as_float((v).y << 16); \
                     A.w += __uint_as_float((v).y & 0xffff0000u); }

__global__ __launch_bounds__(256) void gather_kernel(
    const ushort* __restrict__ hin, ushort* __restrict__ agg,
    const int* __restrict__ row_ptr, const int* __restrict__ pdeg,
    const int* __restrict__ col)
{
    int lane = threadIdx.x & 63;
    int slot = lane >> 4;
    int ch   = (lane & 15) * 4;
    int gwid = (blockIdx.x * blockDim.x + threadIdx.x) >> 6;
    int nwaves = (gridDim.x * blockDim.x) >> 6;

    for (int n0 = gwid * 4; n0 < N_NODES; n0 += nwaves * 4) {
        int n = n0 + slot;
        const int* row = col + row_ptr[n];
        int pd = pdeg[n];
        float4 a0 = {0.f,0.f,0.f,0.f}, a1 = {0.f,0.f,0.f,0.f};
        float4 a2 = {0.f,0.f,0.f,0.f}, a3 = {0.f,0.f,0.f,0.f};
        for (int e = 0; e < pd; e += 8) {
            int4 ca = *(const int4*)(row + e);
            int4 cb = *(const int4*)(row + e + 4);
            uint2 v0 = *(const uint2*)(hin + (size_t)ca.x * HID + ch);
            uint2 v1 = *(const uint2*)(hin + (size_t)ca.y * HID + ch);
            uint2 v2 = *(const uint2*)(hin + (size_t)ca.z * HID + ch);
            uint2 v3 = *(const uint2*)(hin + (size_t)ca.w * HID + ch);
            uint2 v4 = *(const uint2*)(hin + (size_t)cb.x * HID + ch);
            uint2 v5 = *(const uint2*)(hin + (size_t)cb.y * HID + ch);
            uint2 v6 = *(const uint2*)(hin + (size_t)cb.z * HID + ch);
            uint2 v7 = *(const uint2*)(hin + (size_t)cb.w * HID + ch);
            ACC4(a0, v0); ACC4(a1, v1); ACC4(a2, v2); ACC4(a3, v3);
            ACC4(a0, v4); ACC4(a1, v5); ACC4(a2, v6); ACC4(a3, v7);
        }
        a0.x += a1.x + a2.x + a3.x;
        a0.y += a1.y + a2.y + a3.y;
        a0.z += a1.z + a2.z + a3.z;
        a0.w += a1.w + a2.w + a3.w;
        uint2 o;
        o.x = packbf2(a0.x, a0.y);
        o.y = packbf2(a0.z, a0.w);
        *(uint2*)(agg + (size_t)n * HID + ch) = o;
    }
}

// ---------------- transform via MFMA: hout = relu(agg@Wrel + h@Wroot + b) ----------------
// Wave = 16 nodes x 64 out-ch. A frags from h/agg rows (lane&15 = node,
// lane>>4 = k-group of 8). B frags from WT (hoisted, loaded once).
// Epilogue through padded LDS for coalesced bf16 row stores.

__global__ __launch_bounds__(256) void transform_kernel(
    const ushort* __restrict__ hin, const ushort* __restrict__ agg,
    ushort* __restrict__ hout, const ushort* __restrict__ WTl,
    const float* __restrict__ bias)
{
    typedef __attribute__((ext_vector_type(8))) short short8;
    typedef __attribute__((ext_vector_type(4))) float f32x4;
    __shared__ float lds[4][16][68];
    int lane = threadIdx.x & 63;
    int wid  = threadIdx.x >> 6;
    int mrow = lane & 15;
    int kg   = lane >> 4;
    int gw = (blockIdx.x * blockDim.x + threadIdx.x) >> 6;
    int nw = (gridDim.x * blockDim.x) >> 6;

    short8 Bf[4][4];   // [col-tile][rel_h0, rel_h1, root_h0, root_h1]
#pragma unroll
    for (int c = 0; c < 4; c++)
#pragma unroll
        for (int m = 0; m < 2; m++)
#pragma unroll
            for (int h = 0; h < 2; h++)
                Bf[c][m * 2 + h] = *(const short8*)(
                    WTl + m * HID * HID + (c * 16 + mrow) * HID + h * 32 + kg * 8);

    float bv[4];
#pragma unroll
    for (int c = 0; c < 4; c++) bv[c] = bias[c * 16 + mrow];

    for (int ng = gw; ng < N_NODES / 16; ng += nw) {
        size_t rb = ((size_t)ng * 16 + mrow) * HID + kg * 8;
        short8 Ah0 = *(const short8*)(hin + rb);
        short8 Ah1 = *(const short8*)(hin + rb + 32);
        short8 Aa0 = *(const short8*)(agg + rb);
        short8 Aa1 = *(const short8*)(agg + rb + 32);
#pragma unroll
        for (int c = 0; c < 4; c++) {
            f32x4 acc = {0.f, 0.f, 0.f, 0.f};
            acc = __builtin_amdgcn_mfma_f32_16x16x32_bf16(Aa0, Bf[c][0], acc, 0, 0, 0);
            acc = __builtin_amdgcn_mfma_f32_16x16x32_bf16(Aa1, Bf[c][1], acc, 0, 0, 0);
            acc = __builtin_amdgcn_mfma_f32_16x16x32_bf16(Ah0, Bf[c][2], acc, 0, 0, 0);
            acc = __builtin_amdgcn_mfma_f32_16x16x32_bf16(Ah1, Bf[c][3], acc, 0, 0, 0);
#pragma unroll
            for (int r = 0; r < 4; r++)
                lds[wid][kg * 4 + r][c * 16 + mrow] = fmaxf(acc[r] + bv[c], 0.f);
        }
        asm volatile("s_waitcnt lgkmcnt(0)" ::: "memory");
        const float* lr = &lds[wid][mrow][kg * 16];
        float4 f0 = *(const float4*)(lr + 0);
        float4 f1 = *(const float4*)(lr + 4);
        float4 f2 = *(const float4*)(lr + 8);
        float4 f3 = *(const float4*)(lr + 12);
        uint4 o0, o1;
        o0.x = packbf2(f0.x, f0.y); o0.y = packbf2(f0.z, f0.w);
        o0.z = packbf2(f1.x, f1.y); o0.w = packbf2(f1.z, f1.w);
        o1.x = packbf2(f2.x, f2.y); o1.y = packbf2(f2.z, f2.w);
        o1.z = packbf2(f3.x, f3.y); o1.w = packbf2(f3.z, f3.w);
        ushort* orow = hout + ((size_t)ng * 16 + mrow) * HID + kg * 16;
        *(uint4*)(orow) = o0;
        *(uint4*)(orow + 8) = o1;
    }
}

// ---------------- pooling (batch sorted, bf16 h): wave per 64-node chunk ----------------

__global__ __launch_bounds__(256) void pool_kernel(
    const ushort* __restrict__ h, const int* __restrict__ batch,
    float* __restrict__ pooled_ws) {
    const int CH = 64;
    int lane = threadIdx.x & 63;
    int gwid = (blockIdx.x * blockDim.x + threadIdx.x) >> 6;
    int n0 = gwid * CH;
    if (n0 >= N_NODES) return;
    int nend = min(n0 + CH, N_NODES);
    int cur = batch[n0];
    float acc = 0.f;
    for (int n = n0; n < nend; n++) {
        int g = batch[n];
        if (g != cur) {
            atomicAdd(&pooled_ws[cur * HID + lane], acc);
            acc = 0.f;
            cur = g;
        }
        acc += __uint_as_float(((uint)h[(size_t)n * HID + lane]) << 16);
    }
    atomicAdd(&pooled_ws[cur * HID + lane], acc);
}

// ---------------- MLP readout (fp32, also copies pooled -> d_out) ----------------

__global__ void mlp_kernel(const float* __restrict__ pooled_ws,
                           const float* __restrict__ W1, const float* __restrict__ b1,
                           const float* __restrict__ W2, const float* __restrict__ b2,
                           float* __restrict__ out, float* __restrict__ pooled_out) {
    __shared__ float sp[HID];
    __shared__ float red[4];
    int g = blockIdx.x, t = threadIdx.x;
    if (t < HID) {
        float v = pooled_ws[g * HID + t];
        sp[t] = v;
        pooled_out[g * HID + t] = v;
    }
    __syncthreads();
    float acc = b1[t];
#pragma unroll
    for (int k = 0; k < HID; k++) acc = fmaf(sp[k], W1[k * 128 + t], acc);
    float hid = fmaxf(acc, 0.f);
    float p0 = hid * W2[t * 2 + 0];
    float p1 = hid * W2[t * 2 + 1];
    for (int off = 32; off > 0; off >>= 1) {
        p0 += __shfl_down(p0, off, 64);
        p1 += __shfl_down(p1, off, 64);
    }
    int wave = t >> 6, lane = t & 63;
    if (lane == 0) { red[wave * 2 + 0] = p0; red[wave * 2 + 1] = p1; }
    __syncthreads();
    if (t == 0) {
        float o0 = red[0] + red[2] + b2[0];
        float o1 = red[1] + red[3] + b2[1];
        out[g * 2 + 0] = 1.f / (1.f + expf(-o0));
        out[g * 2 + 1] = 1.f / (1.f + expf(-o1));
    }
}

// ---------------- launcher ----------------

extern "C" void kernel_launch(void* const* d_in, const int* in_sizes, int n_in,
                              void* d_out, int out_size, void* d_ws, size_t ws_size,
                              hipStream_t stream) {
    const float* x      = (const float*)d_in[0];
    const int*   ei     = (const int*)d_in[1];
    const int*   batch  = (const int*)d_in[2];
    const float* W_rel  = (const float*)d_in[3];
    const float* W_root = (const float*)d_in[4];
    const float* b_conv = (const float*)d_in[5];
    const float* W1     = (const float*)d_in[6];
    const float* b1     = (const float*)d_in[7];
    const float* W2     = (const float*)d_in[8];
    const float* b2     = (const float*)d_in[9];

    float* outp       = (float*)d_out;                 // [512,2]
    float* pooled_out = (float*)d_out + N_GRAPHS * 2;  // [512,64]

    const size_t HROWS_B = ((size_t)(N_NODES + 1) * HID * 2 + 255) & ~(size_t)255;

    char* ws = (char*)d_ws;
    size_t off = 0;
    ushort* hX = (ushort*)(ws + off); off += HROWS_B;
    ushort* hA = (ushort*)(ws + off); off += HROWS_B;
    ushort* hB = (ushort*)(ws + off); off += HROWS_B;
    ushort* gg = (ushort*)(ws + off); off += ((size_t)N_NODES * HID * 2 + 255) & ~(size_t)255;
    ushort* WT = (ushort*)(ws + off); off += ((size_t)NC * 2 * HID * HID * 2 + 255) & ~(size_t)255;
    uint* part    = (uint*)(ws + off); off += (size_t)NBUCK * PSTRIDE * 4;
    int* colidx   = (int*)(ws + off); off += (size_t)NBUCK * BSTRIDE * 4;
    int* row_ptr  = (int*)(ws + off); off += (size_t)(N_NODES + 4) * 4;
    int* pdeg     = (int*)(ws + off); off += (size_t)(N_NODES + 4) * 4;
    int* ccursor  = (int*)(ws + off); off += (size_t)NBUCK * 4;
    float* pooled_ws = (float*)(ws + off); off += (size_t)N_GRAPHS * HID * 4;

    const int* esrc = ei;
    const int* edst = ei + N_EDGES;

    hipMemsetAsync(ccursor, 0, (size_t)NBUCK * 4, stream);
    hipMemsetAsync(pooled_ws, 0, (size_t)N_GRAPHS * HID * 4, stream);

    cvt_kernel<<<2048, 256, 0, stream>>>(x, hX, hA, hB);
    wprep_kernel<<<(NC * 2 * HID * HID + 255) / 256, 256, 0, stream>>>(W_rel, W_root, WT);

    partition_kernel<<<NPBLK, 512, 0, stream>>>(esrc, edst, ccursor, part);
    bcsr_kernel<<<NBUCK, 256, 0, stream>>>(part, ccursor, row_ptr, pdeg, colidx);

    // layer 1: hX -> hA
    gather_kernel<<<2048, 256, 0, stream>>>(hX, gg, row_ptr, pdeg, colidx);
    transform_kernel<<<512, 256, 0, stream>>>(hX, gg, hA, WT + 0 * 2 * HID * HID, b_conv + 0 * HID);
    // layer 2: hA -> hB
    gather_kernel<<<2048, 256, 0, stream>>>(hA, gg, row_ptr, pdeg, colidx);
    transform_kernel<<<512, 256, 0, stream>>>(hA, gg, hB, WT + 1 * 2 * HID * HID, b_conv + 1 * HID);
    // layer 3: hB -> hA
    gather_kernel<<<2048, 256, 0, stream>>>(hB, gg, row_ptr, pdeg, colidx);
    transform_kernel<<<512, 256, 0, stream>>>(hB, gg, hA, WT + 2 * 2 * HID * HID, b_conv + 2 * HID);

    pool_kernel<<<391, 256, 0, stream>>>(hA, batch, pooled_ws);
    mlp_kernel<<<N_GRAPHS, 128, 0, stream>>>(pooled_ws, W1, b1, W2, b2, outp, pooled_out);
}